// Round 2
// baseline (1907.114 us; speedup 1.0000x reference)
//
#include <hip/hip_runtime.h>
#include <stdint.h>

typedef _Float16 half2_t __attribute__((ext_vector_type(2)));
typedef short bf16x8 __attribute__((ext_vector_type(8)));
typedef float f32x4 __attribute__((ext_vector_type(4)));
typedef unsigned short u16;
typedef unsigned int u32;
typedef unsigned long long u64;

#define B_ 64
#define S_ 512
#define D_ 512
#define H_ 512
#define FF_ 1024
#define C_ 1000

// weight split for k_rnn: pairs [0,PREG) in VGPRs, [PREG,256) in LDS
#define PREG 200
#define PLDS (256 - PREG)          // 56 pairs per column
#define NQ   (PLDS / 4)            // 14 uint4 rows per column

__device__ __forceinline__ u16 f2bf(float f){
  u32 u = __builtin_bit_cast(u32, f);
  u = (u + 0x7FFFu + ((u >> 16) & 1u)) >> 16;
  return (u16)u;
}
__device__ __forceinline__ u32 packh2(float a, float b){
  u16 lo = __builtin_bit_cast(u16, (_Float16)a);
  u16 hi = __builtin_bit_cast(u16, (_Float16)b);
  return (u32)lo | ((u32)hi << 16);
}
__device__ __forceinline__ float fdot2u(u32 a, u32 b, float c){
  return __builtin_amdgcn_fdot2(__builtin_bit_cast(half2_t, a),
                                __builtin_bit_cast(half2_t, b), c, false);
}
__device__ __forceinline__ float h2f(u16 h){
  return (float)__builtin_bit_cast(_Float16, h);
}

// ---- P1: gather emb rows by token, convert f32 -> bf16. Xg [32768][512] ----
__global__ void k_gather(const int* __restrict__ tokens, const float* __restrict__ emb,
                         u16* __restrict__ Xg){
  int c = blockIdx.x * 256 + threadIdx.x;      // 2,097,152 chunks of 8 elems
  int row = c >> 6, seg = c & 63;
  int tok = tokens[row];
  const float4* s = (const float4*)(emb + (size_t)tok * 512 + seg * 8);
  float4 a = s[0], b = s[1];
  uint4 o;
  o.x = (u32)f2bf(a.x) | ((u32)f2bf(a.y) << 16);
  o.y = (u32)f2bf(a.z) | ((u32)f2bf(a.w) << 16);
  o.z = (u32)f2bf(b.x) | ((u32)f2bf(b.y) << 16);
  o.w = (u32)f2bf(b.z) | ((u32)f2bf(b.w) << 16);
  *(uint4*)(Xg + (size_t)row * 512 + seg * 8) = o;
}

// ---- P2: transpose+convert Wx [512k][512n] f32 -> WxT [512n][512k] bf16 ----
__global__ void k_trans_cvt(const float* __restrict__ src, u16* __restrict__ dst){
  __shared__ u16 t[64][65];
  int bx = blockIdx.x & 7, by = blockIdx.x >> 3;
  int tid = threadIdx.x;
  int c = tid & 63, r0 = (tid >> 6) * 16;
  #pragma unroll
  for (int i = 0; i < 16; i++){
    int k = by * 64 + r0 + i, n = bx * 64 + c;
    t[r0 + i][c] = f2bf(src[k * 512 + n]);
  }
  __syncthreads();
  #pragma unroll
  for (int i = 0; i < 16; i++){
    int n = bx * 64 + r0 + i, k = by * 64 + c;
    dst[n * 512 + k] = t[c][r0 + i];
  }
}

// ---- P3: Wh f32 [512k][512j] -> packed half2 pairs, reg-part / LDS-part ----
// pair p in [0,256): k = {2p, 2p+1}. column j in [0,512).
// p <  PREG : Wreg[p*512 + j]
// p >= PREG : pr=p-PREG; c=j>>8; t=j&255; r=c*NQ+(pr>>2); e=pr&3
//             Wlds_u32[(r*256 + t)*4 + e]
__global__ void k_prep_wh(const float* __restrict__ Wh, u32* __restrict__ Wreg,
                          u32* __restrict__ Wlds){
  int x = blockIdx.x * 256 + threadIdx.x;      // 131072
  int p = x >> 9, j = x & 511;
  float w0 = Wh[(2 * p) * 512 + j];
  float w1 = Wh[(2 * p + 1) * 512 + j];
  u32 v = packh2(w0, w1);
  if (p < PREG){
    Wreg[p * 512 + j] = v;
  } else {
    int pr = p - PREG;
    int c = j >> 8, t = j & 255;
    int r = c * NQ + (pr >> 2), e = pr & 3;
    Wlds[(r * 256 + t) * 4 + e] = v;
  }
}

// ---- P5: token mask -> 8 x u64 bitmask per batch ----
__global__ void k_mask(const int* __restrict__ tokens, u64* __restrict__ masks){
  int b = blockIdx.x, tid = threadIdx.x;       // 512 threads
  int tok = tokens[b * 512 + tid];
  u64 m = __ballot(tok != 0);
  if ((tid & 63) == 0) masks[b * 8 + (tid >> 6)] = m;
}

// ---- P4: generic pack K-pairs: dst[p*N+n] = half2(src[2p][n], src[2p+1][n]) ----
__global__ void k_pack_pairs(const float* __restrict__ src, u32* __restrict__ dst, int N){
  int n = blockIdx.x * 256 + threadIdx.x;
  int p = blockIdx.y;
  if (n >= N) return;
  dst[p * N + n] = packh2(src[(2 * p) * N + n], src[(2 * p + 1) * N + n]);
}

// ---- G1: xproj = Xg @ Wx + b_rnn, bf16 MFMA, out f16 [32768][512] ----
__global__ __launch_bounds__(256) void k_gemm(const u16* __restrict__ A, const u16* __restrict__ Bt,
                                              const float* __restrict__ bias, u16* __restrict__ out){
  __shared__ __align__(16) u16 As[128 * 40];
  __shared__ __align__(16) u16 Bs[128 * 40];
  int tid = threadIdx.x;
  int m0 = blockIdx.x * 128, n0 = blockIdx.y * 128;
  int w = tid >> 6, l = tid & 63;
  int wr = w >> 1, wc = w & 1;
  int kg = l >> 4, r16 = l & 15;
  f32x4 acc[4][4];
  #pragma unroll
  for (int mi = 0; mi < 4; mi++)
    #pragma unroll
    for (int ni = 0; ni < 4; ni++) acc[mi][ni] = (f32x4){0.f, 0.f, 0.f, 0.f};
  int srow = tid >> 1, spart = tid & 1;
  for (int kt = 0; kt < 512; kt += 32){
    const uint4* sa = (const uint4*)(A + (size_t)(m0 + srow) * 512 + kt);
    uint4 a0 = sa[spart * 2], a1 = sa[spart * 2 + 1];
    const uint4* sb = (const uint4*)(Bt + (size_t)(n0 + srow) * 512 + kt);
    uint4 b0 = sb[spart * 2], b1 = sb[spart * 2 + 1];
    uint4* da = (uint4*)(As + srow * 40 + spart * 16);
    da[0] = a0; da[1] = a1;
    uint4* db = (uint4*)(Bs + srow * 40 + spart * 16);
    db[0] = b0; db[1] = b1;
    __syncthreads();
    bf16x8 af[4], bfr[4];
    #pragma unroll
    for (int mi = 0; mi < 4; mi++)
      af[mi] = *(const bf16x8*)(As + (wr * 64 + mi * 16 + r16) * 40 + kg * 8);
    #pragma unroll
    for (int ni = 0; ni < 4; ni++)
      bfr[ni] = *(const bf16x8*)(Bs + (wc * 64 + ni * 16 + r16) * 40 + kg * 8);
    #pragma unroll
    for (int mi = 0; mi < 4; mi++)
      #pragma unroll
      for (int ni = 0; ni < 4; ni++)
        acc[mi][ni] = __builtin_amdgcn_mfma_f32_16x16x32_bf16(af[mi], bfr[ni], acc[mi][ni], 0, 0, 0);
    __syncthreads();
  }
  #pragma unroll
  for (int ni = 0; ni < 4; ni++){
    int col = n0 + wc * 64 + ni * 16 + r16;
    float bb = bias[col];
    #pragma unroll
    for (int mi = 0; mi < 4; mi++){
      int mb = m0 + wr * 64 + mi * 16 + kg * 4;
      #pragma unroll
      for (int r = 0; r < 4; r++){
        float v = acc[mi][ni][r] + bb;
        out[(size_t)(mb + r) * 512 + col] = __builtin_bit_cast(u16, (_Float16)v);
      }
    }
  }
}

// ---- R: 512-step RNN scan. 64 blocks (1/batch) x 256 thr (4 waves). ----
// Thread owns columns j0=tid and j1=tid+256. 400 weight half2 in VGPRs,
// 112 KB in LDS. h broadcast from LDS. Mask bits in SGPRs.
__global__ __launch_bounds__(256, 1) void k_rnn(
    const u32* __restrict__ Wreg, const uint4* __restrict__ Wldsg,
    const u16* __restrict__ xproj, const u64* __restrict__ masks,
    u32* __restrict__ hpack){
  __shared__ __align__(16) u32 hbuf[2][256];
  __shared__ __align__(16) uint4 wlds[2 * NQ * 256];   // 112 KB
  int b = blockIdx.x, tid = threadIdx.x;
  u32 w0[PREG], w1[PREG];
  #pragma unroll
  for (int p = 0; p < PREG; p++) w0[p] = Wreg[p * 512 + tid];
  #pragma unroll
  for (int p = 0; p < PREG; p++) w1[p] = Wreg[p * 512 + 256 + tid];
  #pragma unroll
  for (int r = 0; r < 2 * NQ; r++) wlds[r * 256 + tid] = Wldsg[r * 256 + tid];
  hbuf[0][tid] = 0;
  u64 ml[8];
  #pragma unroll
  for (int m = 0; m < 8; m++) ml[m] = masks[b * 8 + m];
  __syncthreads();

  const u16* xp = xproj + (size_t)b * S_ * H_;
  u32 hw0 = 0, hw1 = 0;                       // packed h owned by even threads
  float xp0 = h2f(xp[tid]);
  float xp1 = h2f(xp[256 + tid]);
  for (int t = 0; t < 512; t++){
    u16 nx0 = 0, nx1 = 0;
    if (t < 511){
      nx0 = xp[(t + 1) * 512 + tid];
      nx1 = xp[(t + 1) * 512 + 256 + tid];
    }
    const uint4* hv4 = (const uint4*)hbuf[t & 1];
    float a0 = 0.f, a1 = 0.f, a2 = 0.f, a3 = 0.f;
    float c0 = 0.f, c1 = 0.f, c2 = 0.f, c3 = 0.f;
    #pragma unroll
    for (int g = 0; g < PREG / 4; g++){
      uint4 hv = hv4[g];
      a0 = fdot2u(w0[4 * g + 0], hv.x, a0);
      a1 = fdot2u(w0[4 * g + 1], hv.y, a1);
      a2 = fdot2u(w0[4 * g + 2], hv.z, a2);
      a3 = fdot2u(w0[4 * g + 3], hv.w, a3);
      c0 = fdot2u(w1[4 * g + 0], hv.x, c0);
      c1 = fdot2u(w1[4 * g + 1], hv.y, c1);
      c2 = fdot2u(w1[4 * g + 2], hv.z, c2);
      c3 = fdot2u(w1[4 * g + 3], hv.w, c3);
    }
    #pragma unroll
    for (int pg = 0; pg < NQ; pg++){
      uint4 hv = hv4[PREG / 4 + pg];
      uint4 q0 = wlds[pg * 256 + tid];
      uint4 q1 = wlds[(NQ + pg) * 256 + tid];
      a0 = fdot2u(q0.x, hv.x, a0);
      a1 = fdot2u(q0.y, hv.y, a1);
      a2 = fdot2u(q0.z, hv.z, a2);
      a3 = fdot2u(q0.w, hv.w, a3);
      c0 = fdot2u(q1.x, hv.x, c0);
      c1 = fdot2u(q1.y, hv.y, c1);
      c2 = fdot2u(q1.z, hv.z, c2);
      c3 = fdot2u(q1.w, hv.w, c3);
    }
    float hn0 = fmaxf(xp0 + ((a0 + a1) + (a2 + a3)), 0.f);
    float hn1 = fmaxf(xp1 + ((c0 + c1) + (c2 + c3)), 0.f);
    xp0 = h2f(nx0);
    xp1 = h2f(nx1);
    float o0 = __shfl_xor(hn0, 1);
    float o1 = __shfl_xor(hn1, 1);
    if ((ml[t >> 6] >> (t & 63)) & 1){
      hw0 = packh2(hn0, o0);
      hw1 = packh2(hn1, o1);
    }
    if ((tid & 1) == 0){
      hbuf[(t + 1) & 1][tid >> 1] = hw0;
      hbuf[(t + 1) & 1][128 + (tid >> 1)] = hw1;
    }
    __syncthreads();
  }
  hpack[b * 256 + tid] = hbuf[0][tid];
}

// ---- H1: y1 = relu(h @ W1 + b1), packed output ----
__global__ __launch_bounds__(256) void k_fc1(const u32* __restrict__ hpack, const u32* __restrict__ W1p,
                                             const float* __restrict__ b1, u32* __restrict__ y1p){
  __shared__ u32 hrow[256];
  int b = blockIdx.y, tid = threadIdx.x;
  int n = blockIdx.x * 256 + tid;
  hrow[tid] = hpack[b * 256 + tid];
  __syncthreads();
  float a0 = 0.f, a1 = 0.f;
  #pragma unroll 8
  for (int p = 0; p < 256; p += 2){
    a0 = fdot2u(W1p[p * FF_ + n], hrow[p], a0);
    a1 = fdot2u(W1p[(p + 1) * FF_ + n], hrow[p + 1], a1);
  }
  float acc = fmaxf(a0 + a1 + b1[n], 0.f);
  float other = __shfl_xor(acc, 1);
  if ((tid & 1) == 0) y1p[b * 512 + (n >> 1)] = packh2(acc, other);
}

// ---- H2: y2 = relu(y1 @ W2 + b2), packed output ----
__global__ __launch_bounds__(256) void k_fc2(const u32* __restrict__ y1p, const u32* __restrict__ W2p,
                                             const float* __restrict__ b2, u32* __restrict__ y2p){
  __shared__ u32 yrow[512];
  int b = blockIdx.y, tid = threadIdx.x;
  int n = blockIdx.x * 256 + tid;
  yrow[tid] = y1p[b * 512 + tid];
  yrow[tid + 256] = y1p[b * 512 + 256 + tid];
  __syncthreads();
  float a0 = 0.f, a1 = 0.f;
  #pragma unroll 8
  for (int p = 0; p < 512; p += 2){
    a0 = fdot2u(W2p[p * FF_ + n], yrow[p], a0);
    a1 = fdot2u(W2p[(p + 1) * FF_ + n], yrow[p + 1], a1);
  }
  float acc = fmaxf(a0 + a1 + b2[n], 0.f);
  float other = __shfl_xor(acc, 1);
  if ((tid & 1) == 0) y2p[b * 512 + (n >> 1)] = packh2(acc, other);
}

// ---- H3: z = y2 @ Wo + bo, softmax, write f32 output [64][1000] ----
__global__ __launch_bounds__(256) void k_out(const u32* __restrict__ y2p, const u32* __restrict__ Wop,
                                             const float* __restrict__ bo, float* __restrict__ out){
  __shared__ u32 yrow[512];
  __shared__ float redm[4], reds[4];
  int b = blockIdx.x, tid = threadIdx.x;
  yrow[tid] = y2p[b * 512 + tid];
  yrow[tid + 256] = y2p[b * 512 + 256 + tid];
  __syncthreads();
  int n0 = tid, n1 = tid + 256, n2 = tid + 512, n3 = tid + 768;
  bool v3 = n3 < C_;
  int n3c = v3 ? n3 : 0;
  float z0 = 0.f, z1 = 0.f, z2 = 0.f, z3 = 0.f;
  #pragma unroll 4
  for (int p = 0; p < 512; p++){
    u32 y = yrow[p];
    z0 = fdot2u(Wop[p * C_ + n0], y, z0);
    z1 = fdot2u(Wop[p * C_ + n1], y, z1);
    z2 = fdot2u(Wop[p * C_ + n2], y, z2);
    z3 = fdot2u(Wop[p * C_ + n3c], y, z3);
  }
  z0 += bo[n0]; z1 += bo[n1]; z2 += bo[n2]; z3 += bo[n3c];
  float mx = fmaxf(fmaxf(z0, z1), z2);
  if (v3) mx = fmaxf(mx, z3);
  #pragma unroll
  for (int o = 1; o < 64; o <<= 1) mx = fmaxf(mx, __shfl_xor(mx, o));
  if ((tid & 63) == 0) redm[tid >> 6] = mx;
  __syncthreads();
  mx = fmaxf(fmaxf(redm[0], redm[1]), fmaxf(redm[2], redm[3]));
  float e0 = __expf(z0 - mx), e1 = __expf(z1 - mx), e2 = __expf(z2 - mx);
  float e3 = v3 ? __expf(z3 - mx) : 0.f;
  float s = e0 + e1 + e2 + e3;
  #pragma unroll
  for (int o = 1; o < 64; o <<= 1) s += __shfl_xor(s, o);
  if ((tid & 63) == 0) reds[tid >> 6] = s;
  __syncthreads();
  s = reds[0] + reds[1] + reds[2] + reds[3];
  float inv = 1.0f / s;
  out[b * C_ + n0] = e0 * inv;
  out[b * C_ + n1] = e1 * inv;
  out[b * C_ + n2] = e2 * inv;
  if (v3) out[b * C_ + n3] = e3 * inv;
}

extern "C" void kernel_launch(void* const* d_in, const int* in_sizes, int n_in,
                              void* d_out, int out_size, void* d_ws, size_t ws_size,
                              hipStream_t stream) {
  const int*   tokens = (const int*)d_in[0];
  const float* emb    = (const float*)d_in[1];
  const float* Wx     = (const float*)d_in[2];
  const float* Wh     = (const float*)d_in[3];
  const float* brnn   = (const float*)d_in[4];
  const float* W1     = (const float*)d_in[5];
  const float* b1     = (const float*)d_in[6];
  const float* W2     = (const float*)d_in[7];
  const float* b2     = (const float*)d_in[8];
  const float* Wo     = (const float*)d_in[9];
  const float* bo     = (const float*)d_in[10];
  float* out = (float*)d_out;

  char* ws = (char*)d_ws;
  size_t off = 0;
  auto alloc = [&](size_t bytes) -> void* {
    void* p = ws + off;
    off += (bytes + 255) & ~(size_t)255;
    return p;
  };
  u16* Xg     = (u16*)alloc((size_t)32768 * 512 * 2);     // gathered emb, bf16
  u16* WxT    = (u16*)alloc((size_t)512 * 512 * 2);       // Wx transposed, bf16
  u16* xproj  = (u16*)alloc((size_t)32768 * 512 * 2);     // x@Wx + b, f16
  u32* Wreg   = (u32*)alloc((size_t)PREG * 512 * 4);      // Wh reg-part, half2
  uint4* Wlds = (uint4*)alloc((size_t)2 * NQ * 256 * 16); // Wh LDS-part
  u64* masks  = (u64*)alloc((size_t)64 * 8 * 8);          // token!=0 bitmasks
  u32* W1p    = (u32*)alloc((size_t)256 * 1024 * 4);
  u32* W2p    = (u32*)alloc((size_t)512 * 1024 * 4);
  u32* Wop    = (u32*)alloc((size_t)512 * 1000 * 4);
  u32* hpack  = (u32*)alloc((size_t)64 * 256 * 4);
  u32* y1p    = (u32*)alloc((size_t)64 * 512 * 4);
  u32* y2p    = (u32*)alloc((size_t)64 * 512 * 4);

  k_gather<<<dim3(8192), dim3(256), 0, stream>>>(tokens, emb, Xg);
  k_trans_cvt<<<dim3(64), dim3(256), 0, stream>>>(Wx, WxT);
  k_prep_wh<<<dim3(512), dim3(256), 0, stream>>>(Wh, Wreg, (u32*)Wlds);
  k_mask<<<dim3(64), dim3(512), 0, stream>>>(tokens, masks);
  k_pack_pairs<<<dim3(4, 256), dim3(256), 0, stream>>>(W1, W1p, 1024);
  k_pack_pairs<<<dim3(4, 512), dim3(256), 0, stream>>>(W2, W2p, 1024);
  k_pack_pairs<<<dim3(4, 512), dim3(256), 0, stream>>>(Wo, Wop, 1000);
  k_gemm<<<dim3(256, 4), dim3(256), 0, stream>>>(Xg, WxT, brnn, xproj);
  k_rnn<<<dim3(64), dim3(256), 0, stream>>>(Wreg, Wlds, xproj, masks, hpack);
  k_fc1<<<dim3(4, 64), dim3(256), 0, stream>>>(hpack, W1p, b1, y1p);
  k_fc2<<<dim3(4, 64), dim3(256), 0, stream>>>(y1p, W2p, b2, y2p);
  k_out<<<dim3(64), dim3(256), 0, stream>>>(y2p, Wop, bo, out);
}

// Round 3
// 938.602 us; speedup vs baseline: 2.0319x; 2.0319x over previous
//
#include <hip/hip_runtime.h>
#include <stdint.h>

typedef _Float16 half2_t __attribute__((ext_vector_type(2)));
typedef short bf16x8 __attribute__((ext_vector_type(8)));
typedef float f32x4 __attribute__((ext_vector_type(4)));
typedef unsigned short u16;
typedef unsigned int u32;
typedef unsigned long long u64;

#define B_ 64
#define S_ 512
#define D_ 512
#define H_ 512
#define FF_ 1024
#define C_ 1000

// scaling: W' = 16*Wh (fp8), g = 64*h (fp8). g_new = relu(64*xp + (g@W')/16)
#define WSCALE 16.0f
#define HSCALE 64.0f

__device__ __forceinline__ u16 f2bf(float f){
  u32 u = __builtin_bit_cast(u32, f);
  u = (u + 0x7FFFu + ((u >> 16) & 1u)) >> 16;
  return (u16)u;
}
__device__ __forceinline__ u32 packh2(float a, float b){
  u16 lo = __builtin_bit_cast(u16, (_Float16)a);
  u16 hi = __builtin_bit_cast(u16, (_Float16)b);
  return (u32)lo | ((u32)hi << 16);
}
__device__ __forceinline__ float fdot2u(u32 a, u32 b, float c){
  return __builtin_amdgcn_fdot2(__builtin_bit_cast(half2_t, a),
                                __builtin_bit_cast(half2_t, b), c, false);
}
__device__ __forceinline__ float h2f(u16 h){
  return (float)__builtin_bit_cast(_Float16, h);
}

// ---- P1: gather emb rows by token, convert f32 -> bf16. Xg [32768][512] ----
__global__ void k_gather(const int* __restrict__ tokens, const float* __restrict__ emb,
                         u16* __restrict__ Xg){
  int c = blockIdx.x * 256 + threadIdx.x;
  int row = c >> 6, seg = c & 63;
  int tok = tokens[row];
  const float4* s = (const float4*)(emb + (size_t)tok * 512 + seg * 8);
  float4 a = s[0], b = s[1];
  uint4 o;
  o.x = (u32)f2bf(a.x) | ((u32)f2bf(a.y) << 16);
  o.y = (u32)f2bf(a.z) | ((u32)f2bf(a.w) << 16);
  o.z = (u32)f2bf(b.x) | ((u32)f2bf(b.y) << 16);
  o.w = (u32)f2bf(b.z) | ((u32)f2bf(b.w) << 16);
  *(uint4*)(Xg + (size_t)row * 512 + seg * 8) = o;
}

// ---- P2: transpose+convert Wx [512k][512n] f32 -> WxT [512n][512k] bf16 ----
__global__ void k_trans_cvt(const float* __restrict__ src, u16* __restrict__ dst){
  __shared__ u16 t[64][65];
  int bx = blockIdx.x & 7, by = blockIdx.x >> 3;
  int tid = threadIdx.x;
  int c = tid & 63, r0 = (tid >> 6) * 16;
  #pragma unroll
  for (int i = 0; i < 16; i++){
    int k = by * 64 + r0 + i, n = bx * 64 + c;
    t[r0 + i][c] = f2bf(src[k * 512 + n]);
  }
  __syncthreads();
  #pragma unroll
  for (int i = 0; i < 16; i++){
    int n = bx * 64 + r0 + i, k = by * 64 + c;
    dst[n * 512 + k] = t[c][r0 + i];
  }
}

// ---- P3: Wh f32 -> fp8 e4m3 (x16), laid out as MFMA B-fragments ----
// B-frag for mfma 16x16x32: lane l holds B[k][n], n = l&15, k = (l>>4)*8 + j.
// Wave wv owns columns n in [wv*128, wv*128+128). w[nt*16+kt] per thread.
// Global layout: Wf[(nt*16+kt)*256 + wv*64 + l]  (u64 each, 8 fp8)
__global__ void k_prep_wfp8(const float* __restrict__ Wh, u64* __restrict__ Wf){
  int tid = blockIdx.x * 256 + threadIdx.x;     // 32768 threads
  int col = tid & 15;
  int nt  = (tid >> 4) & 7;
  int wv  = (tid >> 7) & 3;
  int q   = (tid >> 9) & 3;
  int kt  = (tid >> 11) & 15;
  int l = q * 16 + col;
  int n = wv * 128 + nt * 16 + col;
  int kb = kt * 32 + q * 8;
  float f[8];
  #pragma unroll
  for (int j = 0; j < 8; j++) f[j] = Wh[(size_t)(kb + j) * 512 + n] * WSCALE;
  u32 lo = __builtin_amdgcn_cvt_pk_fp8_f32(f[0], f[1], 0, false);
  lo = __builtin_amdgcn_cvt_pk_fp8_f32(f[2], f[3], lo, true);
  u32 hi = __builtin_amdgcn_cvt_pk_fp8_f32(f[4], f[5], 0, false);
  hi = __builtin_amdgcn_cvt_pk_fp8_f32(f[6], f[7], hi, true);
  Wf[(size_t)(nt * 16 + kt) * 256 + wv * 64 + l] = (u64)lo | ((u64)hi << 32);
}

// ---- P5: token mask -> byte per step ----
__global__ void k_mask(const int* __restrict__ tokens, unsigned char* __restrict__ masks8){
  int i = blockIdx.x * 256 + threadIdx.x;       // 32768
  masks8[i] = (tokens[i] != 0) ? 1 : 0;
}

// ---- P4: generic pack K-pairs: dst[p*N+n] = half2(src[2p][n], src[2p+1][n]) ----
__global__ void k_pack_pairs(const float* __restrict__ src, u32* __restrict__ dst, int N){
  int n = blockIdx.x * 256 + threadIdx.x;
  int p = blockIdx.y;
  if (n >= N) return;
  dst[p * N + n] = packh2(src[(2 * p) * N + n], src[(2 * p + 1) * N + n]);
}

// ---- G1: xproj64 = 64*(Xg @ Wx + b_rnn), bf16 MFMA, out f16 [32768][512] ----
__global__ __launch_bounds__(256) void k_gemm(const u16* __restrict__ A, const u16* __restrict__ Bt,
                                              const float* __restrict__ bias, u16* __restrict__ out){
  __shared__ __align__(16) u16 As[128 * 40];
  __shared__ __align__(16) u16 Bs[128 * 40];
  int tid = threadIdx.x;
  int m0 = blockIdx.x * 128, n0 = blockIdx.y * 128;
  int w = tid >> 6, l = tid & 63;
  int wr = w >> 1, wc = w & 1;
  int kg = l >> 4, r16 = l & 15;
  f32x4 acc[4][4];
  #pragma unroll
  for (int mi = 0; mi < 4; mi++)
    #pragma unroll
    for (int ni = 0; ni < 4; ni++) acc[mi][ni] = (f32x4){0.f, 0.f, 0.f, 0.f};
  int srow = tid >> 1, spart = tid & 1;
  for (int kt = 0; kt < 512; kt += 32){
    const uint4* sa = (const uint4*)(A + (size_t)(m0 + srow) * 512 + kt);
    uint4 a0 = sa[spart * 2], a1 = sa[spart * 2 + 1];
    const uint4* sb = (const uint4*)(Bt + (size_t)(n0 + srow) * 512 + kt);
    uint4 b0 = sb[spart * 2], b1 = sb[spart * 2 + 1];
    uint4* da = (uint4*)(As + srow * 40 + spart * 16);
    da[0] = a0; da[1] = a1;
    uint4* db = (uint4*)(Bs + srow * 40 + spart * 16);
    db[0] = b0; db[1] = b1;
    __syncthreads();
    bf16x8 af[4], bfr[4];
    #pragma unroll
    for (int mi = 0; mi < 4; mi++)
      af[mi] = *(const bf16x8*)(As + (wr * 64 + mi * 16 + r16) * 40 + kg * 8);
    #pragma unroll
    for (int ni = 0; ni < 4; ni++)
      bfr[ni] = *(const bf16x8*)(Bs + (wc * 64 + ni * 16 + r16) * 40 + kg * 8);
    #pragma unroll
    for (int mi = 0; mi < 4; mi++)
      #pragma unroll
      for (int ni = 0; ni < 4; ni++)
        acc[mi][ni] = __builtin_amdgcn_mfma_f32_16x16x32_bf16(af[mi], bfr[ni], acc[mi][ni], 0, 0, 0);
    __syncthreads();
  }
  #pragma unroll
  for (int ni = 0; ni < 4; ni++){
    int col = n0 + wc * 64 + ni * 16 + r16;
    float bb = bias[col];
    #pragma unroll
    for (int mi = 0; mi < 4; mi++){
      int mb = m0 + wr * 64 + mi * 16 + kg * 4;
      #pragma unroll
      for (int r = 0; r < 4; r++){
        float v = (acc[mi][ni][r] + bb) * HSCALE;
        out[(size_t)(mb + r) * 512 + col] = __builtin_bit_cast(u16, (_Float16)v);
      }
    }
  }
}

// ---- R: 512-step RNN scan via fp8 MFMA. 64 blocks x 256 thr (4 waves, 1/SIMD). ----
// Wh' (fp8, x16) fully register-resident: 128 u64 B-fragments per thread (AGPRs).
// g = 64*h lives as fp8[512] in LDS; A-fragment address depends only on k, so all
// M-rows replicate g -> every lane's acc[nt][0] = g_new[col] after MFMA.
__global__ __launch_bounds__(256, 1) void k_rnn(
    const u64* __restrict__ Wf, const u16* __restrict__ xproj64,
    const unsigned char* __restrict__ masks8, u32* __restrict__ hpack){
  __shared__ __align__(8) unsigned char g8[512];
  __shared__ unsigned char msk[512];
  int b = blockIdx.x, tid = threadIdx.x;
  int wv = tid >> 6, l = tid & 63;
  int col = l & 15, q = l >> 4;

  long wgt[128];
  #pragma unroll
  for (int i = 0; i < 128; i++)
    wgt[i] = ((const long*)Wf)[(size_t)i * 256 + wv * 64 + l];

  msk[tid] = masks8[b * 512 + tid];
  msk[tid + 256] = masks8[b * 512 + 256 + tid];
  if (tid < 128) ((u32*)g8)[tid] = 0;
  __syncthreads();

  const u16* xp = xproj64 + (size_t)b * S_ * H_;
  int n0 = wv * 128;
  float xpre[8];
  #pragma unroll
  for (int nt = 0; nt < 8; nt++) xpre[nt] = h2f(xp[n0 + nt * 16 + col]);

  #pragma unroll 1
  for (int t = 0; t < 512; t++){
    // A-fragments for this step (k-only addressing; 4 distinct addrs/wave)
    long a[16];
    #pragma unroll
    for (int kt = 0; kt < 16; kt++)
      a[kt] = *(const long*)(g8 + kt * 32 + q * 8);
    bool wr = msk[t] != 0;
    __syncthreads();   // reads done before anyone overwrites g8

    f32x4 acc[8];
    #pragma unroll
    for (int nt = 0; nt < 8; nt++) acc[nt] = (f32x4){0.f, 0.f, 0.f, 0.f};
    #pragma unroll
    for (int kt = 0; kt < 16; kt++)
      #pragma unroll
      for (int nt = 0; nt < 8; nt++)
        acc[nt] = __builtin_amdgcn_mfma_f32_16x16x32_fp8_fp8(
            a[kt], wgt[nt * 16 + kt], acc[nt], 0, 0, 0);

    // prefetch next step's xp (latency hidden under next step's MFMAs)
    int tn = t < 511 ? t + 1 : 511;
    float xnx[8];
    #pragma unroll
    for (int nt = 0; nt < 8; nt++)
      xnx[nt] = h2f(xp[(size_t)tn * 512 + n0 + nt * 16 + col]);

    #pragma unroll
    for (int nt = 0; nt < 8; nt++){
      float hn = fmaxf(xpre[nt] + acc[nt][0] * (1.0f / WSCALE), 0.f);
      if (wr && q == 0){
        u32 pk = __builtin_amdgcn_cvt_pk_fp8_f32(hn, hn, 0, false);
        g8[n0 + nt * 16 + col] = (unsigned char)(pk & 0xFF);
      }
      xpre[nt] = xnx[nt];
    }
    __syncthreads();   // writes visible before next step's reads
  }

  // h = g/64 -> f16 pairs
  u32 two = *(const u16*)(g8 + tid * 2);
  float f0 = __builtin_amdgcn_cvt_f32_fp8(two, 0) * (1.0f / HSCALE);
  float f1 = __builtin_amdgcn_cvt_f32_fp8(two, 1) * (1.0f / HSCALE);
  hpack[b * 256 + tid] = packh2(f0, f1);
}

// ---- H1: y1 = relu(h @ W1 + b1), packed output ----
__global__ __launch_bounds__(256) void k_fc1(const u32* __restrict__ hpack, const u32* __restrict__ W1p,
                                             const float* __restrict__ b1, u32* __restrict__ y1p){
  __shared__ u32 hrow[256];
  int b = blockIdx.y, tid = threadIdx.x;
  int n = blockIdx.x * 256 + tid;
  hrow[tid] = hpack[b * 256 + tid];
  __syncthreads();
  float a0 = 0.f, a1 = 0.f;
  #pragma unroll 8
  for (int p = 0; p < 256; p += 2){
    a0 = fdot2u(W1p[p * FF_ + n], hrow[p], a0);
    a1 = fdot2u(W1p[(p + 1) * FF_ + n], hrow[p + 1], a1);
  }
  float acc = fmaxf(a0 + a1 + b1[n], 0.f);
  float other = __shfl_xor(acc, 1);
  if ((tid & 1) == 0) y1p[b * 512 + (n >> 1)] = packh2(acc, other);
}

// ---- H2: y2 = relu(y1 @ W2 + b2), packed output ----
__global__ __launch_bounds__(256) void k_fc2(const u32* __restrict__ y1p, const u32* __restrict__ W2p,
                                             const float* __restrict__ b2, u32* __restrict__ y2p){
  __shared__ u32 yrow[512];
  int b = blockIdx.y, tid = threadIdx.x;
  int n = blockIdx.x * 256 + tid;
  yrow[tid] = y1p[b * 512 + tid];
  yrow[tid + 256] = y1p[b * 512 + 256 + tid];
  __syncthreads();
  float a0 = 0.f, a1 = 0.f;
  #pragma unroll 8
  for (int p = 0; p < 512; p += 2){
    a0 = fdot2u(W2p[p * FF_ + n], yrow[p], a0);
    a1 = fdot2u(W2p[(p + 1) * FF_ + n], yrow[p + 1], a1);
  }
  float acc = fmaxf(a0 + a1 + b2[n], 0.f);
  float other = __shfl_xor(acc, 1);
  if ((tid & 1) == 0) y2p[b * 512 + (n >> 1)] = packh2(acc, other);
}

// ---- H3: z = y2 @ Wo + bo, softmax, write f32 output [64][1000] ----
__global__ __launch_bounds__(256) void k_out(const u32* __restrict__ y2p, const u32* __restrict__ Wop,
                                             const float* __restrict__ bo, float* __restrict__ out){
  __shared__ u32 yrow[512];
  __shared__ float redm[4], reds[4];
  int b = blockIdx.x, tid = threadIdx.x;
  yrow[tid] = y2p[b * 512 + tid];
  yrow[tid + 256] = y2p[b * 512 + 256 + tid];
  __syncthreads();
  int n0 = tid, n1 = tid + 256, n2 = tid + 512, n3 = tid + 768;
  bool v3 = n3 < C_;
  int n3c = v3 ? n3 : 0;
  float z0 = 0.f, z1 = 0.f, z2 = 0.f, z3 = 0.f;
  #pragma unroll 4
  for (int p = 0; p < 512; p++){
    u32 y = yrow[p];
    z0 = fdot2u(Wop[p * C_ + n0], y, z0);
    z1 = fdot2u(Wop[p * C_ + n1], y, z1);
    z2 = fdot2u(Wop[p * C_ + n2], y, z2);
    z3 = fdot2u(Wop[p * C_ + n3c], y, z3);
  }
  z0 += bo[n0]; z1 += bo[n1]; z2 += bo[n2]; z3 += bo[n3c];
  float mx = fmaxf(fmaxf(z0, z1), z2);
  if (v3) mx = fmaxf(mx, z3);
  #pragma unroll
  for (int o = 1; o < 64; o <<= 1) mx = fmaxf(mx, __shfl_xor(mx, o));
  if ((tid & 63) == 0) redm[tid >> 6] = mx;
  __syncthreads();
  mx = fmaxf(fmaxf(redm[0], redm[1]), fmaxf(redm[2], redm[3]));
  float e0 = __expf(z0 - mx), e1 = __expf(z1 - mx), e2 = __expf(z2 - mx);
  float e3 = v3 ? __expf(z3 - mx) : 0.f;
  float s = e0 + e1 + e2 + e3;
  #pragma unroll
  for (int o = 1; o < 64; o <<= 1) s += __shfl_xor(s, o);
  if ((tid & 63) == 0) reds[tid >> 6] = s;
  __syncthreads();
  s = reds[0] + reds[1] + reds[2] + reds[3];
  float inv = 1.0f / s;
  out[b * C_ + n0] = e0 * inv;
  out[b * C_ + n1] = e1 * inv;
  out[b * C_ + n2] = e2 * inv;
  if (v3) out[b * C_ + n3] = e3 * inv;
}

extern "C" void kernel_launch(void* const* d_in, const int* in_sizes, int n_in,
                              void* d_out, int out_size, void* d_ws, size_t ws_size,
                              hipStream_t stream) {
  const int*   tokens = (const int*)d_in[0];
  const float* emb    = (const float*)d_in[1];
  const float* Wx     = (const float*)d_in[2];
  const float* Wh     = (const float*)d_in[3];
  const float* brnn   = (const float*)d_in[4];
  const float* W1     = (const float*)d_in[5];
  const float* b1     = (const float*)d_in[6];
  const float* W2     = (const float*)d_in[7];
  const float* b2     = (const float*)d_in[8];
  const float* Wo     = (const float*)d_in[9];
  const float* bo     = (const float*)d_in[10];
  float* out = (float*)d_out;

  char* ws = (char*)d_ws;
  size_t off = 0;
  auto alloc = [&](size_t bytes) -> void* {
    void* p = ws + off;
    off += (bytes + 255) & ~(size_t)255;
    return p;
  };
  u16* Xg     = (u16*)alloc((size_t)32768 * 512 * 2);   // gathered emb, bf16
  u16* WxT    = (u16*)alloc((size_t)512 * 512 * 2);     // Wx transposed, bf16
  u16* xproj  = (u16*)alloc((size_t)32768 * 512 * 2);   // 64*(x@Wx + b), f16
  u64* Wf     = (u64*)alloc((size_t)32768 * 8);         // Wh fp8 B-fragments
  unsigned char* masks8 = (unsigned char*)alloc(32768); // token!=0 bytes
  u32* W1p    = (u32*)alloc((size_t)256 * 1024 * 4);
  u32* W2p    = (u32*)alloc((size_t)512 * 1024 * 4);
  u32* Wop    = (u32*)alloc((size_t)512 * 1000 * 4);
  u32* hpack  = (u32*)alloc((size_t)64 * 256 * 4);
  u32* y1p    = (u32*)alloc((size_t)64 * 512 * 4);
  u32* y2p    = (u32*)alloc((size_t)64 * 512 * 4);

  k_gather<<<dim3(8192), dim3(256), 0, stream>>>(tokens, emb, Xg);
  k_trans_cvt<<<dim3(64), dim3(256), 0, stream>>>(Wx, WxT);
  k_prep_wfp8<<<dim3(128), dim3(256), 0, stream>>>(Wh, Wf);
  k_mask<<<dim3(128), dim3(256), 0, stream>>>(tokens, masks8);
  k_pack_pairs<<<dim3(4, 256), dim3(256), 0, stream>>>(W1, W1p, 1024);
  k_pack_pairs<<<dim3(4, 512), dim3(256), 0, stream>>>(W2, W2p, 1024);
  k_pack_pairs<<<dim3(4, 512), dim3(256), 0, stream>>>(Wo, Wop, 1000);
  k_gemm<<<dim3(256, 4), dim3(256), 0, stream>>>(Xg, WxT, brnn, xproj);
  k_rnn<<<dim3(64), dim3(256), 0, stream>>>(Wf, xproj, masks8, hpack);
  k_fc1<<<dim3(4, 64), dim3(256), 0, stream>>>(hpack, W1p, b1, y1p);
  k_fc2<<<dim3(4, 64), dim3(256), 0, stream>>>(y1p, W2p, b2, y2p);
  k_out<<<dim3(64), dim3(256), 0, stream>>>(y2p, Wop, bo, out);
}

// Round 4
// 510.244 us; speedup vs baseline: 3.7377x; 1.8395x over previous
//
#include <hip/hip_runtime.h>
#include <stdint.h>

typedef _Float16 half2_t __attribute__((ext_vector_type(2)));
typedef short bf16x8 __attribute__((ext_vector_type(8)));
typedef float f32x4 __attribute__((ext_vector_type(4)));
typedef int i32x4 __attribute__((ext_vector_type(4)));
typedef unsigned short u16;
typedef unsigned int u32;
typedef unsigned long long u64;

#define B_ 64
#define S_ 512
#define D_ 512
#define H_ 512
#define FF_ 1024
#define C_ 1000

// scaling: Wq = round(1024*Wh) i8, g = round(1536*h) i8 in [0,127]
// g_new = relu(1536*xp + (g . Wq)/1024)
#define SW 1024.0f
#define SH 1536.0f

__device__ __forceinline__ u16 f2bf(float f){
  u32 u = __builtin_bit_cast(u32, f);
  u = (u + 0x7FFFu + ((u >> 16) & 1u)) >> 16;
  return (u16)u;
}
__device__ __forceinline__ u32 packh2(float a, float b){
  u16 lo = __builtin_bit_cast(u16, (_Float16)a);
  u16 hi = __builtin_bit_cast(u16, (_Float16)b);
  return (u32)lo | ((u32)hi << 16);
}
__device__ __forceinline__ float fdot2u(u32 a, u32 b, float c){
  return __builtin_amdgcn_fdot2(__builtin_bit_cast(half2_t, a),
                                __builtin_bit_cast(half2_t, b), c, false);
}
__device__ __forceinline__ float h2f(u16 h){
  return (float)__builtin_bit_cast(_Float16, h);
}

// ---- P1: gather emb rows by token, convert f32 -> bf16. Xg [32768][512] ----
__global__ void k_gather(const int* __restrict__ tokens, const float* __restrict__ emb,
                         u16* __restrict__ Xg){
  int c = blockIdx.x * 256 + threadIdx.x;
  int row = c >> 6, seg = c & 63;
  int tok = tokens[row];
  const float4* s = (const float4*)(emb + (size_t)tok * 512 + seg * 8);
  float4 a = s[0], b = s[1];
  uint4 o;
  o.x = (u32)f2bf(a.x) | ((u32)f2bf(a.y) << 16);
  o.y = (u32)f2bf(a.z) | ((u32)f2bf(a.w) << 16);
  o.z = (u32)f2bf(b.x) | ((u32)f2bf(b.y) << 16);
  o.w = (u32)f2bf(b.z) | ((u32)f2bf(b.w) << 16);
  *(uint4*)(Xg + (size_t)row * 512 + seg * 8) = o;
}

// ---- P2: transpose+convert Wx [512k][512n] f32 -> WxT [512n][512k] bf16 ----
__global__ void k_trans_cvt(const float* __restrict__ src, u16* __restrict__ dst){
  __shared__ u16 t[64][65];
  int bx = blockIdx.x & 7, by = blockIdx.x >> 3;
  int tid = threadIdx.x;
  int c = tid & 63, r0 = (tid >> 6) * 16;
  #pragma unroll
  for (int i = 0; i < 16; i++){
    int k = by * 64 + r0 + i, n = bx * 64 + c;
    t[r0 + i][c] = f2bf(src[k * 512 + n]);
  }
  __syncthreads();
  #pragma unroll
  for (int i = 0; i < 16; i++){
    int n = bx * 64 + r0 + i, k = by * 64 + c;
    dst[n * 512 + k] = t[c][r0 + i];
  }
}

// ---- P3: Wh f32 -> i8 (x1024), laid out as 16x16x64 i8 MFMA B-fragments ----
// B-frag: lane l holds B[k][n], n = l&15, k = (l>>4)*16 + j, j=0..15 (uint4).
// frag id f = wv*32 + ntl*8 + kt; col n = wv*64 + ntl*16 + (l&15);
// k = kt*64 + (l>>4)*16 + j.  Wf[f*64 + l] (16 bytes each).
__global__ void k_prep_wi8(const float* __restrict__ Wh, uint4* __restrict__ Wf){
  int gtid = blockIdx.x * 256 + threadIdx.x;   // 16384
  int fid = gtid >> 6, l = gtid & 63;
  int wv = fid >> 5, ntl = (fid >> 3) & 3, kt = fid & 7;
  int n = wv * 64 + ntl * 16 + (l & 15);
  int k0 = kt * 64 + (l >> 4) * 16;
  u32 d[4];
  #pragma unroll
  for (int dw = 0; dw < 4; dw++){
    u32 acc = 0;
    #pragma unroll
    for (int j = 0; j < 4; j++){
      float w = Wh[(size_t)(k0 + dw * 4 + j) * 512 + n] * SW;
      int q = (int)fminf(fmaxf(rintf(w), -127.f), 127.f);
      acc |= ((u32)(q & 0xFF)) << (8 * j);
    }
    d[dw] = acc;
  }
  uint4 o; o.x = d[0]; o.y = d[1]; o.z = d[2]; o.w = d[3];
  Wf[(size_t)fid * 64 + l] = o;
}

// ---- P5: token mask -> byte per step ----
__global__ void k_mask(const int* __restrict__ tokens, unsigned char* __restrict__ masks8){
  int i = blockIdx.x * 256 + threadIdx.x;       // 32768
  masks8[i] = (tokens[i] != 0) ? 1 : 0;
}

// ---- P4: generic pack K-pairs: dst[p*N+n] = half2(src[2p][n], src[2p+1][n]) ----
__global__ void k_pack_pairs(const float* __restrict__ src, u32* __restrict__ dst, int N){
  int n = blockIdx.x * 256 + threadIdx.x;
  int p = blockIdx.y;
  if (n >= N) return;
  dst[p * N + n] = packh2(src[(2 * p) * N + n], src[(2 * p + 1) * N + n]);
}

// ---- G1: xproj = SH*(Xg @ Wx + b_rnn), bf16 MFMA, out f16 [32768][512] ----
__global__ __launch_bounds__(256) void k_gemm(const u16* __restrict__ A, const u16* __restrict__ Bt,
                                              const float* __restrict__ bias, u16* __restrict__ out){
  __shared__ __align__(16) u16 As[128 * 40];
  __shared__ __align__(16) u16 Bs[128 * 40];
  int tid = threadIdx.x;
  int m0 = blockIdx.x * 128, n0 = blockIdx.y * 128;
  int w = tid >> 6, l = tid & 63;
  int wr = w >> 1, wc = w & 1;
  int kg = l >> 4, r16 = l & 15;
  f32x4 acc[4][4];
  #pragma unroll
  for (int mi = 0; mi < 4; mi++)
    #pragma unroll
    for (int ni = 0; ni < 4; ni++) acc[mi][ni] = (f32x4){0.f, 0.f, 0.f, 0.f};
  int srow = tid >> 1, spart = tid & 1;
  for (int kt = 0; kt < 512; kt += 32){
    const uint4* sa = (const uint4*)(A + (size_t)(m0 + srow) * 512 + kt);
    uint4 a0 = sa[spart * 2], a1 = sa[spart * 2 + 1];
    const uint4* sb = (const uint4*)(Bt + (size_t)(n0 + srow) * 512 + kt);
    uint4 b0 = sb[spart * 2], b1 = sb[spart * 2 + 1];
    uint4* da = (uint4*)(As + srow * 40 + spart * 16);
    da[0] = a0; da[1] = a1;
    uint4* db = (uint4*)(Bs + srow * 40 + spart * 16);
    db[0] = b0; db[1] = b1;
    __syncthreads();
    bf16x8 af[4], bfr[4];
    #pragma unroll
    for (int mi = 0; mi < 4; mi++)
      af[mi] = *(const bf16x8*)(As + (wr * 64 + mi * 16 + r16) * 40 + kg * 8);
    #pragma unroll
    for (int ni = 0; ni < 4; ni++)
      bfr[ni] = *(const bf16x8*)(Bs + (wc * 64 + ni * 16 + r16) * 40 + kg * 8);
    #pragma unroll
    for (int mi = 0; mi < 4; mi++)
      #pragma unroll
      for (int ni = 0; ni < 4; ni++)
        acc[mi][ni] = __builtin_amdgcn_mfma_f32_16x16x32_bf16(af[mi], bfr[ni], acc[mi][ni], 0, 0, 0);
    __syncthreads();
  }
  #pragma unroll
  for (int ni = 0; ni < 4; ni++){
    int col = n0 + wc * 64 + ni * 16 + r16;
    float bb = bias[col];
    #pragma unroll
    for (int mi = 0; mi < 4; mi++){
      int mb = m0 + wr * 64 + mi * 16 + kg * 4;
      #pragma unroll
      for (int r = 0; r < 4; r++){
        float v = (acc[mi][ni][r] + bb) * SH;
        out[(size_t)(mb + r) * 512 + col] = __builtin_bit_cast(u16, (_Float16)v);
      }
    }
  }
}

// ---- R: 512-step RNN scan via i8 MFMA. 64 blocks x 512 thr (8 waves, 2/SIMD). ----
// Wave wv owns cols [wv*64, wv*64+64). Weights: 32 B-frags/thread (VGPR/AGPR).
// g (i8, x1536) double-buffered in LDS; A-frag addr depends only on k -> all
// 16 M-rows replicate g -> acc[nt][0] = g_new pre-activation for the col.
__global__ __launch_bounds__(512, 2) void k_rnn(
    const uint4* __restrict__ Wf, const u16* __restrict__ xproj,
    const unsigned char* __restrict__ masks8, u32* __restrict__ hpack){
  __shared__ __align__(16) unsigned char g8[2][512];
  __shared__ unsigned char msk[512];
  int b = blockIdx.x, tid = threadIdx.x;
  int wv = tid >> 6, l = tid & 63;
  int q = l >> 4;

  i32x4 wgt[32];                                // f = ntl*8 + kt
  #pragma unroll
  for (int f = 0; f < 32; f++)
    wgt[f] = ((const i32x4*)Wf)[(size_t)(wv * 32 + f) * 64 + l];

  msk[tid] = masks8[b * 512 + tid];
  g8[0][tid] = 0;
  __syncthreads();

  const u16* xp = xproj + (size_t)b * S_ * H_;
  int nown = wv * 64 + l;                       // this lane's owned column
  float xpf = h2f(xp[nown]);
  u32 greg = 0;                                 // current quantized byte for nown

  #pragma unroll 2
  for (int t = 0; t < 512; t++){
    const unsigned char* gc = g8[t & 1];
    i32x4 a0c = *(const i32x4*)(gc + 0 * 64 + q * 16);
    i32x4 a1c = *(const i32x4*)(gc + 1 * 64 + q * 16);
    i32x4 a2c = *(const i32x4*)(gc + 2 * 64 + q * 16);
    i32x4 a3c = *(const i32x4*)(gc + 3 * 64 + q * 16);
    i32x4 a4c = *(const i32x4*)(gc + 4 * 64 + q * 16);
    i32x4 a5c = *(const i32x4*)(gc + 5 * 64 + q * 16);
    i32x4 a6c = *(const i32x4*)(gc + 6 * 64 + q * 16);
    i32x4 a7c = *(const i32x4*)(gc + 7 * 64 + q * 16);

    i32x4 acc0 = (i32x4){0,0,0,0}, acc1 = (i32x4){0,0,0,0};
    i32x4 acc2 = (i32x4){0,0,0,0}, acc3 = (i32x4){0,0,0,0};
    #define STEPK(AK, KT) \
      acc0 = __builtin_amdgcn_mfma_i32_16x16x64_i8(AK, wgt[0 * 8 + KT], acc0, 0, 0, 0); \
      acc1 = __builtin_amdgcn_mfma_i32_16x16x64_i8(AK, wgt[1 * 8 + KT], acc1, 0, 0, 0); \
      acc2 = __builtin_amdgcn_mfma_i32_16x16x64_i8(AK, wgt[2 * 8 + KT], acc2, 0, 0, 0); \
      acc3 = __builtin_amdgcn_mfma_i32_16x16x64_i8(AK, wgt[3 * 8 + KT], acc3, 0, 0, 0);
    STEPK(a0c, 0) STEPK(a1c, 1) STEPK(a2c, 2) STEPK(a3c, 3)
    STEPK(a4c, 4) STEPK(a5c, 5) STEPK(a6c, 6) STEPK(a7c, 7)
    #undef STEPK

    u16 xn = 0;
    if (t < 511) xn = xp[(size_t)(t + 1) * 512 + nown];

    int av = (q == 0) ? acc0[0] : (q == 1) ? acc1[0] : (q == 2) ? acc2[0] : acc3[0];
    float gn = fmaxf(fmaf((float)av, 1.0f / SW, xpf), 0.f);
    u32 q8 = (u32)(int)fminf(rintf(gn), 127.f);
    if (msk[t]) greg = q8;
    g8[(t + 1) & 1][nown] = (unsigned char)greg;
    xpf = h2f(xn);
    __syncthreads();
  }

  // h = g/SH -> f16 pairs (final state in g8[0])
  if (tid < 256){
    float f0 = (float)g8[0][2 * tid] * (1.0f / SH);
    float f1 = (float)g8[0][2 * tid + 1] * (1.0f / SH);
    hpack[b * 256 + tid] = packh2(f0, f1);
  }
}

// ---- H1: y1 = relu(h @ W1 + b1), packed output ----
__global__ __launch_bounds__(256) void k_fc1(const u32* __restrict__ hpack, const u32* __restrict__ W1p,
                                             const float* __restrict__ b1, u32* __restrict__ y1p){
  __shared__ u32 hrow[256];
  int b = blockIdx.y, tid = threadIdx.x;
  int n = blockIdx.x * 256 + tid;
  hrow[tid] = hpack[b * 256 + tid];
  __syncthreads();
  float a0 = 0.f, a1 = 0.f;
  #pragma unroll 8
  for (int p = 0; p < 256; p += 2){
    a0 = fdot2u(W1p[p * FF_ + n], hrow[p], a0);
    a1 = fdot2u(W1p[(p + 1) * FF_ + n], hrow[p + 1], a1);
  }
  float acc = fmaxf(a0 + a1 + b1[n], 0.f);
  float other = __shfl_xor(acc, 1);
  if ((tid & 1) == 0) y1p[b * 512 + (n >> 1)] = packh2(acc, other);
}

// ---- H2: y2 = relu(y1 @ W2 + b2), packed output ----
__global__ __launch_bounds__(256) void k_fc2(const u32* __restrict__ y1p, const u32* __restrict__ W2p,
                                             const float* __restrict__ b2, u32* __restrict__ y2p){
  __shared__ u32 yrow[512];
  int b = blockIdx.y, tid = threadIdx.x;
  int n = blockIdx.x * 256 + tid;
  yrow[tid] = y1p[b * 512 + tid];
  yrow[tid + 256] = y1p[b * 512 + 256 + tid];
  __syncthreads();
  float a0 = 0.f, a1 = 0.f;
  #pragma unroll 8
  for (int p = 0; p < 512; p += 2){
    a0 = fdot2u(W2p[p * FF_ + n], yrow[p], a0);
    a1 = fdot2u(W2p[(p + 1) * FF_ + n], yrow[p + 1], a1);
  }
  float acc = fmaxf(a0 + a1 + b2[n], 0.f);
  float other = __shfl_xor(acc, 1);
  if ((tid & 1) == 0) y2p[b * 512 + (n >> 1)] = packh2(acc, other);
}

// ---- H3: z = y2 @ Wo + bo, softmax, write f32 output [64][1000] ----
__global__ __launch_bounds__(256) void k_out(const u32* __restrict__ y2p, const u32* __restrict__ Wop,
                                             const float* __restrict__ bo, float* __restrict__ out){
  __shared__ u32 yrow[512];
  __shared__ float redm[4], reds[4];
  int b = blockIdx.x, tid = threadIdx.x;
  yrow[tid] = y2p[b * 512 + tid];
  yrow[tid + 256] = y2p[b * 512 + 256 + tid];
  __syncthreads();
  int n0 = tid, n1 = tid + 256, n2 = tid + 512, n3 = tid + 768;
  bool v3 = n3 < C_;
  int n3c = v3 ? n3 : 0;
  float z0 = 0.f, z1 = 0.f, z2 = 0.f, z3 = 0.f;
  #pragma unroll 4
  for (int p = 0; p < 512; p++){
    u32 y = yrow[p];
    z0 = fdot2u(Wop[p * C_ + n0], y, z0);
    z1 = fdot2u(Wop[p * C_ + n1], y, z1);
    z2 = fdot2u(Wop[p * C_ + n2], y, z2);
    z3 = fdot2u(Wop[p * C_ + n3c], y, z3);
  }
  z0 += bo[n0]; z1 += bo[n1]; z2 += bo[n2]; z3 += bo[n3c];
  float mx = fmaxf(fmaxf(z0, z1), z2);
  if (v3) mx = fmaxf(mx, z3);
  #pragma unroll
  for (int o = 1; o < 64; o <<= 1) mx = fmaxf(mx, __shfl_xor(mx, o));
  if ((tid & 63) == 0) redm[tid >> 6] = mx;
  __syncthreads();
  mx = fmaxf(fmaxf(redm[0], redm[1]), fmaxf(redm[2], redm[3]));
  float e0 = __expf(z0 - mx), e1 = __expf(z1 - mx), e2 = __expf(z2 - mx);
  float e3 = v3 ? __expf(z3 - mx) : 0.f;
  float s = e0 + e1 + e2 + e3;
  #pragma unroll
  for (int o = 1; o < 64; o <<= 1) s += __shfl_xor(s, o);
  if ((tid & 63) == 0) reds[tid >> 6] = s;
  __syncthreads();
  s = reds[0] + reds[1] + reds[2] + reds[3];
  float inv = 1.0f / s;
  out[b * C_ + n0] = e0 * inv;
  out[b * C_ + n1] = e1 * inv;
  out[b * C_ + n2] = e2 * inv;
  if (v3) out[b * C_ + n3] = e3 * inv;
}

extern "C" void kernel_launch(void* const* d_in, const int* in_sizes, int n_in,
                              void* d_out, int out_size, void* d_ws, size_t ws_size,
                              hipStream_t stream) {
  const int*   tokens = (const int*)d_in[0];
  const float* emb    = (const float*)d_in[1];
  const float* Wx     = (const float*)d_in[2];
  const float* Wh     = (const float*)d_in[3];
  const float* brnn   = (const float*)d_in[4];
  const float* W1     = (const float*)d_in[5];
  const float* b1     = (const float*)d_in[6];
  const float* W2     = (const float*)d_in[7];
  const float* b2     = (const float*)d_in[8];
  const float* Wo     = (const float*)d_in[9];
  const float* bo     = (const float*)d_in[10];
  float* out = (float*)d_out;

  char* ws = (char*)d_ws;
  size_t off = 0;
  auto alloc = [&](size_t bytes) -> void* {
    void* p = ws + off;
    off += (bytes + 255) & ~(size_t)255;
    return p;
  };
  u16* Xg     = (u16*)alloc((size_t)32768 * 512 * 2);   // gathered emb, bf16
  u16* WxT    = (u16*)alloc((size_t)512 * 512 * 2);     // Wx transposed, bf16
  u16* xproj  = (u16*)alloc((size_t)32768 * 512 * 2);   // SH*(x@Wx + b), f16
  uint4* Wf   = (uint4*)alloc((size_t)256 * 64 * 16);   // Wh i8 B-fragments
  unsigned char* masks8 = (unsigned char*)alloc(32768); // token!=0 bytes
  u32* W1p    = (u32*)alloc((size_t)256 * 1024 * 4);
  u32* W2p    = (u32*)alloc((size_t)512 * 1024 * 4);
  u32* Wop    = (u32*)alloc((size_t)512 * 1000 * 4);
  u32* hpack  = (u32*)alloc((size_t)64 * 256 * 4);
  u32* y1p    = (u32*)alloc((size_t)64 * 512 * 4);
  u32* y2p    = (u32*)alloc((size_t)64 * 512 * 4);

  k_gather<<<dim3(8192), dim3(256), 0, stream>>>(tokens, emb, Xg);
  k_trans_cvt<<<dim3(64), dim3(256), 0, stream>>>(Wx, WxT);
  k_prep_wi8<<<dim3(64), dim3(256), 0, stream>>>(Wh, Wf);
  k_mask<<<dim3(128), dim3(256), 0, stream>>>(tokens, masks8);
  k_pack_pairs<<<dim3(4, 256), dim3(256), 0, stream>>>(W1, W1p, 1024);
  k_pack_pairs<<<dim3(4, 512), dim3(256), 0, stream>>>(W2, W2p, 1024);
  k_pack_pairs<<<dim3(4, 512), dim3(256), 0, stream>>>(Wo, Wop, 1000);
  k_gemm<<<dim3(256, 4), dim3(256), 0, stream>>>(Xg, WxT, brnn, xproj);
  k_rnn<<<dim3(64), dim3(512), 0, stream>>>(Wf, xproj, masks8, hpack);
  k_fc1<<<dim3(4, 64), dim3(256), 0, stream>>>(hpack, W1p, b1, y1p);
  k_fc2<<<dim3(4, 64), dim3(256), 0, stream>>>(y1p, W2p, b2, y2p);
  k_out<<<dim3(64), dim3(256), 0, stream>>>(y2p, Wop, bo, out);
}